// Round 7
// baseline (389.489 us; speedup 1.0000x reference)
//
#include <hip/hip_runtime.h>

#define TB 8
#define TC 64
#define TT 300
#define TDD 161
#define TH 128
#define TO 64
#define TN (TB * TDD)          // 1288 sequences
#define TWOH 256
#define TILE 16
#define NBLK 81                // ceil(1288/16)
#define NKS 6                  // (C+H)/32
#define ODCH (TO * TDD)        // 10304 channels
#define TOTAL (TB * TO * TT * TDD)      // 24729600
#define AFRAG (NKS * 4 * 16 * 8)        // 3072 ushorts per A-frag buffer
#define TDIAG 50               // diagnostic step count

typedef __attribute__((ext_vector_type(8))) short bf16x8;
typedef __attribute__((ext_vector_type(4))) float f32x4;

#define MFMA __builtin_amdgcn_mfma_f32_16x16x32_bf16

__device__ __forceinline__ ushort f2bf(float f) {
  union { float f; unsigned u; } v; v.f = f;
  return (ushort)((v.u + 0x7fffu + ((v.u >> 16) & 1u)) >> 16);  // RNE
}
__device__ __forceinline__ unsigned pk2bf(float lo, float hi) {
  unsigned r;
  asm("v_cvt_pk_bf16_f32 %0, %1, %2" : "=v"(r) : "v"(lo), "v"(hi));
  return r;  // low16 = bf16(lo), high16 = bf16(hi), RNE
}

// k-mapping inside a 16x16x32 fragment; identical convention for A and B so
// any permutation error cancels in the contraction (verified R1/R2/R4).
__device__ __forceinline__ int kmap(int e, int q) {
  return ((e < 4) ? 0 : 16) + q * 4 + (e & 3);
}
// Swizzled ushort index of (row, kg) in the A-frag buffer (kg in [0,192)).
__device__ __forceinline__ int aidx_sw(int row, int kg) {
  int ks = kg >> 5, k32 = kg & 31;
  int half = k32 >> 4, qq = (k32 >> 2) & 3, em = k32 & 3;
  int B = (ks * 4 + qq) * 16 + (row ^ qq);
  return B * 8 + half * 4 + em;
}

// V=0: full kernel. Diagnostics (write only ws): V=1 skeleton (LDS+barrier+x),
// V=2 +gate MFMAs, V=3 +gates (no y-path). Identical loop structure.
template<int V>
__global__ __launch_bounds__(512) void gru_kernel(
    const float* __restrict__ x, const int* __restrict__ lengths,
    const float* __restrict__ Wx, const float* __restrict__ Wh,
    const float* __restrict__ bias, const float* __restrict__ Wo,
    const float* __restrict__ bo, float* __restrict__ yout,
    float* __restrict__ wsStats, float* __restrict__ diag, int nsteps)
{
  __shared__ __align__(16) ushort ldsA[2][AFRAG];  // double-buffered [x_t | h] frags
  __shared__ float ytile[8][16 * 17 + 4];          // per-wave y transpose staging
  __shared__ int s_b[TILE], s_d[TILE], s_len[TILE], s_ok[TILE];

  const int tid = threadIdx.x;
  const int w = tid >> 6, l = tid & 63, q = l >> 4, r = l & 15;
  const int rxq = r ^ q;

  if (tid < TILE) {
    int n = blockIdx.x * TILE + tid;
    int ok = (n < TN) ? 1 : 0;
    int b = ok ? (n / TDD) : 0;
    int d = ok ? (n - b * TDD) : 0;
    s_b[tid] = b; s_d[tid] = d; s_ok[tid] = ok;
    s_len[tid] = ok ? lengths[b] : -1;
  }
  // zero the h-part (ushort idx >= 1024) of buffer 0 (h_{-1} = 0)
  for (int i = tid; i < AFRAG - 1024; i += 512) ldsA[0][1024 + i] = 0;
  __syncthreads();

  // ---- x loader mapping: thread -> (c = tid/8, nn = (tid%8)*2 + {0,1})
  const int xc = tid >> 3;
  const int xn0 = (tid & 7) * 2;
  int xok[2], xbase[2], xa[2];
  #pragma unroll
  for (int j = 0; j < 2; j++) {
    int nn = xn0 + j;
    xok[j] = s_ok[nn];
    xbase[j] = (s_b[nn] * TC + xc) * (TT * TDD) + s_d[nn];
    xa[j] = aidx_sw(nn, xc);
  }
  #pragma unroll
  for (int j = 0; j < 2; j++) {
    float v = xok[j] ? x[xbase[j]] : 0.0f;
    ldsA[0][xa[j]] = f2bf(v);
  }
  float wx0 = xok[0] ? x[xbase[0] + 1 * TDD] : 0.0f;
  float wx1 = xok[1] ? x[xbase[1] + 1 * TDD] : 0.0f;
  float sx0 = xok[0] ? x[xbase[0] + 2 * TDD] : 0.0f;
  float sx1 = xok[1] ? x[xbase[1] + 2 * TDD] : 0.0f;
  float tx0 = xok[0] ? x[xbase[0] + 3 * TDD] : 0.0f;
  float tx1 = xok[1] ? x[xbase[1] + 3 * TDD] : 0.0f;

  // ---- gate B-fragments from [Wx; Wh] (registers, loaded once).
  // c-gate columns (jj=1) pre-scaled by 2 (exact pow2): tanh(p)=1-2/(e^{2p}+1)
  // with 2p accumulated directly -> saves a v_mul per gate.
  bf16x8 wf[2][NKS];
  const int ucol = w * 16 + r;
  #pragma unroll
  for (int jj = 0; jj < 2; jj++) {
    int col = jj * TH + ucol;
    float sc = jj ? 2.0f : 1.0f;
    #pragma unroll
    for (int ks = 0; ks < NKS; ks++) {
      bf16x8 f;
      #pragma unroll
      for (int e = 0; e < 8; e++) {
        int kg = ks * 32 + kmap(e, q);
        float v = (kg < TC) ? Wx[kg * TWOH + col] : Wh[(kg - TC) * TWOH + col];
        f[e] = (short)f2bf(sc * v);
      }
      wf[jj][ks] = f;
    }
  }
  const float bz = bias[ucol];
  const float bc = 2.0f * bias[TH + ucol];

  // ---- y B-frags (all 8 waves; groups alternate t-parity), o = (w&3)*16+r
  bf16x8 wo[4];
  #pragma unroll
  for (int ks = 0; ks < 4; ks++) {
    bf16x8 f;
    #pragma unroll
    for (int e = 0; e < 8; e++)
      f[e] = (short)f2bf(Wo[(ks * 32 + kmap(e, q)) * TO + ((w & 3) * 16 + r)]);
    wo[ks] = f;
  }
  const float bo_v = bo[(w & 3) * 16 + r];

  int llen[4];
  #pragma unroll
  for (int i = 0; i < 4; i++) llen[i] = s_len[q * 4 + i];

  // transposed-store info: lane handles n = l&15, o_j = (w&3)*16 + (l>>4) + 4j
  const int nT = l & 15;
  const int dT = s_d[nT], lenT = s_len[nT], okT = s_ok[nT];
  int ybaseT[4], ochT[4];
  #pragma unroll
  for (int j = 0; j < 4; j++) {
    int oj = (w & 3) * 16 + (l >> 4) + 4 * j;
    ybaseT[j] = (s_b[nT] * TO + oj) * (TT * TDD) + dT;
    ochT[j] = oj * TDD + dT;
  }
  float ysumT[4] = {0, 0, 0, 0}, ysqT[4] = {0, 0, 0, 0};

  float hreg[4] = {0, 0, 0, 0};
  int hwi[4];
  #pragma unroll
  for (int i = 0; i < 4; i++) hwi[i] = aidx_sw(q * 4 + i, TC + ucol);
  __syncthreads();

#define YPATH(TM_, A2, A3, A4, A5)                                             \
  {                                                                            \
    f32x4 ya = {bo_v, bo_v, bo_v, bo_v}, yb = {0, 0, 0, 0};                    \
    ya = MFMA(A2, wo[0], ya, 0, 0, 0);                                         \
    yb = MFMA(A3, wo[1], yb, 0, 0, 0);                                         \
    ya = MFMA(A4, wo[2], ya, 0, 0, 0);                                         \
    yb = MFMA(A5, wo[3], yb, 0, 0, 0);                                         \
    float* yt = &ytile[w][0];                                                  \
    _Pragma("unroll")                                                          \
    for (int i = 0; i < 4; i++) yt[r * 17 + q * 4 + i] = ya[i] + yb[i];        \
    const int tm = (TM_);                                                      \
    _Pragma("unroll")                                                          \
    for (int j = 0; j < 4; j++) {                                              \
      float v = yt[((l >> 4) + 4 * j) * 17 + nT];                              \
      if (okT) yout[ybaseT[j] + tm * TDD] = v;                                 \
      bool val = (tm < lenT);                                                  \
      ysumT[j] += val ? v : 0.0f;                                              \
      ysqT[j]  += val ? v * v : 0.0f;                                          \
    }                                                                          \
  }

#define STEP(T_, PAR)                                                          \
  {                                                                            \
    const int t_ = (T_);                                                       \
    int tc = t_ + 4; tc = (tc < TT) ? tc : (TT - 1);                           \
    float nx0 = xok[0] ? x[xbase[0] + tc * TDD] : 0.0f;                        \
    float nx1 = xok[1] ? x[xbase[1] + tc * TDD] : 0.0f;                        \
    const ushort* Ab = ldsA[PAR];                                              \
    bf16x8 af0 = *(const bf16x8*)&Ab[((0 * 4 + q) * 16 + rxq) * 8];            \
    bf16x8 af1 = *(const bf16x8*)&Ab[((1 * 4 + q) * 16 + rxq) * 8];            \
    bf16x8 af2 = *(const bf16x8*)&Ab[((2 * 4 + q) * 16 + rxq) * 8];            \
    bf16x8 af3 = *(const bf16x8*)&Ab[((3 * 4 + q) * 16 + rxq) * 8];            \
    bf16x8 af4 = *(const bf16x8*)&Ab[((4 * 4 + q) * 16 + rxq) * 8];            \
    bf16x8 af5 = *(const bf16x8*)&Ab[((5 * 4 + q) * 16 + rxq) * 8];            \
    if constexpr (V == 1) {                                                    \
      asm volatile("" :: "v"(af0), "v"(af1), "v"(af2), "v"(af3),               \
                         "v"(af4), "v"(af5));                                  \
    }                                                                          \
    f32x4 az, az2, ac, ac2;                                                    \
    if constexpr (V == 0 || V >= 2) {                                          \
      az  = f32x4{bz, bz, bz, bz}; az2 = f32x4{0, 0, 0, 0};                    \
      ac  = f32x4{bc, bc, bc, bc}; ac2 = f32x4{0, 0, 0, 0};                    \
      __builtin_amdgcn_s_setprio(1);                                           \
      az  = MFMA(af0, wf[0][0], az,  0, 0, 0);                                 \
      az2 = MFMA(af1, wf[0][1], az2, 0, 0, 0);                                 \
      ac  = MFMA(af0, wf[1][0], ac,  0, 0, 0);                                 \
      ac2 = MFMA(af1, wf[1][1], ac2, 0, 0, 0);                                 \
      az  = MFMA(af2, wf[0][2], az,  0, 0, 0);                                 \
      az2 = MFMA(af3, wf[0][3], az2, 0, 0, 0);                                 \
      ac  = MFMA(af2, wf[1][2], ac,  0, 0, 0);                                 \
      ac2 = MFMA(af3, wf[1][3], ac2, 0, 0, 0);                                 \
      az  = MFMA(af4, wf[0][4], az,  0, 0, 0);                                 \
      az2 = MFMA(af5, wf[0][5], az2, 0, 0, 0);                                 \
      ac  = MFMA(af4, wf[1][4], ac,  0, 0, 0);                                 \
      ac2 = MFMA(af5, wf[1][5], ac2, 0, 0, 0);                                 \
      __builtin_amdgcn_s_setprio(0);                                           \
    }                                                                          \
    if constexpr (V == 0) {                                                    \
      if (((PAR) ? (w < 4) : (w >= 4)) && t_ > 0) {                            \
        YPATH(t_ - 1, af2, af3, af4, af5)                                      \
      }                                                                        \
    }                                                                          \
    unsigned hp01, hp23;                                                       \
    if constexpr (V == 0 || V == 3) {                                          \
      _Pragma("unroll")                                                        \
      for (int i = 0; i < 4; i++) {                                            \
        float a_ = az[i] + az2[i];                                             \
        float b_ = ac[i] + ac2[i];         /* = 2*preact_c */                  \
        float zv = __builtin_amdgcn_rcpf(1.0f + __expf(-a_));                  \
        float hc = 1.0f - 2.0f * __builtin_amdgcn_rcpf(1.0f + __expf(b_));     \
        float h  = hc + zv * (hreg[i] - hc);                                   \
        hreg[i] = (t_ < llen[i]) ? h : hreg[i];                                \
      }                                                                        \
      hp01 = pk2bf(hreg[0], hreg[1]);                                          \
      hp23 = pk2bf(hreg[2], hreg[3]);                                          \
    } else if constexpr (V == 2) {                                             \
      asm volatile("" :: "v"(ac), "v"(ac2));                                   \
      hp01 = pk2bf(az[0] + az2[0], az[1] + az2[1]);                            \
      hp23 = pk2bf(az[2] + az2[2], az[3] + az2[3]);                            \
    } else {                                                                   \
      hp01 = pk2bf(hreg[0], hreg[1]);                                          \
      hp23 = pk2bf(hreg[2], hreg[3]);                                          \
    }                                                                          \
    ushort* Aw = ldsA[(PAR) ^ 1];                                              \
    Aw[hwi[0]] = (ushort)hp01; Aw[hwi[1]] = (ushort)(hp01 >> 16);              \
    Aw[hwi[2]] = (ushort)hp23; Aw[hwi[3]] = (ushort)(hp23 >> 16);              \
    unsigned xp = pk2bf(wx0, wx1);                                             \
    Aw[xa[0]] = (ushort)xp; Aw[xa[1]] = (ushort)(xp >> 16);                    \
    wx0 = sx0; wx1 = sx1; sx0 = tx0; sx1 = tx1; tx0 = nx0; tx1 = nx1;          \
    asm volatile("s_waitcnt lgkmcnt(0)" ::: "memory");                         \
    __builtin_amdgcn_s_barrier();                                              \
    __builtin_amdgcn_sched_barrier(0);                                         \
  }

  for (int t = 0; t < nsteps; t += 2) {
    STEP(t, 0)
    STEP(t + 1, 1)
  }
#undef STEP

  if constexpr (V == 0) {
    // epilogue: y_{TT-1}; h_{TT-1} frags in buffer 0 (TT even), waves 4-7
    if (w >= 4) {
      const ushort* Ab = ldsA[0];
      bf16x8 ah0 = *(const bf16x8*)&Ab[((2 * 4 + q) * 16 + rxq) * 8];
      bf16x8 ah1 = *(const bf16x8*)&Ab[((3 * 4 + q) * 16 + rxq) * 8];
      bf16x8 ah2 = *(const bf16x8*)&Ab[((4 * 4 + q) * 16 + rxq) * 8];
      bf16x8 ah3 = *(const bf16x8*)&Ab[((5 * 4 + q) * 16 + rxq) * 8];
      YPATH(TT - 1, ah0, ah1, ah2, ah3)
    }
    #pragma unroll
    for (int j = 0; j < 4; j++) {
      if (okT) {
        atomicAdd(&wsStats[ochT[j]], ysumT[j]);
        atomicAdd(&wsStats[ODCH + ochT[j]], ysqT[j]);
      }
    }
  } else {
    diag[blockIdx.x * 512 + tid] = hreg[0] + hreg[1] + hreg[2] + hreg[3];
  }
#undef YPATH
}

// ---------------- BN finalize: per-channel scale/shift ------------------
__global__ __launch_bounds__(256) void finalize_kernel(
    const int* __restrict__ lengths, const float* __restrict__ gamma,
    const float* __restrict__ beta, float* __restrict__ wsStats)
{
  int ch = blockIdx.x * 256 + threadIdx.x;
  if (ch >= ODCH) return;
  int c = 0;
  #pragma unroll
  for (int b = 0; b < TB; b++) c += lengths[b];
  float inv = 1.0f / (float)c;
  float mean = wsStats[ch] * inv;
  float var = wsStats[ODCH + ch] * inv - mean * mean;
  float sc = rsqrtf(var + 1e-5f) * gamma[ch];
  wsStats[2 * ODCH + ch] = sc;
  wsStats[3 * ODCH + ch] = beta[ch] - mean * sc;
}

// ---------------- normalize (float4, scale/shift table) ------------------
__global__ __launch_bounds__(256) void norm_kernel(
    const int* __restrict__ lengths, const float* __restrict__ ss,
    float* __restrict__ out)
{
  int i4 = blockIdx.x * 256 + threadIdx.x;   // TOTAL/4 exact
  int idx = i4 * 4;
  float vv[4];
  *(float4*)vv = ((const float4*)out)[i4];
  int dq = idx / TDD; int d = idx - dq * TDD;
  int tq = dq / TT;   int tt = dq - tq * TT;
  int o = tq & 63;    int b = tq >> 6;
  float res[4];
  #pragma unroll
  for (int k = 0; k < 4; k++) {
    int ch = o * TDD + d;
    float r_ = 0.0f;
    if (tt < lengths[b])
      r_ = vv[k] * ss[ch] + ss[ODCH + ch];
    res[k] = r_;
    d++;
    if (d == TDD) { d = 0; tt++; if (tt == TT) { tt = 0; o++; if (o == 64) { o = 0; b++; } } }
  }
  ((float4*)out)[i4] = *(float4*)res;
}

extern "C" void kernel_launch(void* const* d_in, const int* in_sizes, int n_in,
                              void* d_out, int out_size, void* d_ws, size_t ws_size,
                              hipStream_t stream)
{
  const float* x       = (const float*)d_in[0];
  const int*   lengths = (const int*)d_in[1];
  const float* Wx      = (const float*)d_in[2];
  const float* Wh      = (const float*)d_in[3];
  const float* bias    = (const float*)d_in[4];
  const float* Wo      = (const float*)d_in[5];
  const float* bo      = (const float*)d_in[6];
  const float* gamma   = (const float*)d_in[7];
  const float* beta    = (const float*)d_in[8];
  float* out = (float*)d_out;
  float* wsStats = (float*)d_ws;             // 4*ODCH floats
  float* diag = wsStats + 4 * ODCH;          // 81*512 floats scratch

  hipMemsetAsync(wsStats, 0, 2 * ODCH * sizeof(float), stream);
  hipLaunchKernelGGL((gru_kernel<0>), dim3(NBLK), dim3(512), 0, stream,
                     x, lengths, Wx, Wh, bias, Wo, bo, out, wsStats, diag, TT);
  // diagnostics: identical loop structure, 50 steps, write only ws
  hipLaunchKernelGGL((gru_kernel<1>), dim3(NBLK), dim3(512), 0, stream,
                     x, lengths, Wx, Wh, bias, Wo, bo, out, wsStats, diag, TDIAG);
  hipLaunchKernelGGL((gru_kernel<2>), dim3(NBLK), dim3(512), 0, stream,
                     x, lengths, Wx, Wh, bias, Wo, bo, out, wsStats, diag, TDIAG);
  hipLaunchKernelGGL((gru_kernel<3>), dim3(NBLK), dim3(512), 0, stream,
                     x, lengths, Wx, Wh, bias, Wo, bo, out, wsStats, diag, TDIAG);
  hipLaunchKernelGGL(finalize_kernel, dim3((ODCH + 255) / 256), dim3(256), 0, stream,
                     lengths, gamma, beta, wsStats);
  hipLaunchKernelGGL(norm_kernel, dim3(TOTAL / 4 / 256), dim3(256), 0, stream,
                     lengths, wsStats + 2 * ODCH, out);
}